// Round 6
// baseline (2538.520 us; speedup 1.0000x reference)
//
#include <hip/hip_runtime.h>
#include <hip/hip_fp8.h>

#define N_ROWS 4096
#define H_DIM  1024
#define V_SIZE 32000

typedef int   i32x4  __attribute__((ext_vector_type(4)));
typedef int   i32x8  __attribute__((ext_vector_type(8)));
typedef float f32x16 __attribute__((ext_vector_type(16)));

typedef __attribute__((address_space(1))) void* gas_ptr;
typedef __attribute__((address_space(3))) void* las_ptr;

__global__ void zero_f32(float* __restrict__ p, int n) {
  int i = blockIdx.x * blockDim.x + threadIdx.x;
  if (i < n) p[i] = 0.0f;
}

__device__ __forceinline__ unsigned pk4_fp8(float a, float b, float c, float d) {
#if __has_builtin(__builtin_amdgcn_cvt_pk_fp8_f32)
  int v = __builtin_amdgcn_cvt_pk_fp8_f32(a, b, 0, false);
  v = __builtin_amdgcn_cvt_pk_fp8_f32(c, d, v, true);
  return (unsigned)v;
#else
  __hip_fp8_e4m3 qa(a), qb(b), qc(c), qd(d);
  return (unsigned)qa.__x | ((unsigned)qb.__x << 8) | ((unsigned)qc.__x << 16) |
         ((unsigned)qd.__x << 24);
#endif
}

// fp32 -> fp8 e4m3 with the LDS swizzle PRE-BAKED into the HBM layout:
// out[row*1024 + (k ^ ((row&7)<<4))] = fp8(in[row*1024 + k]).
// Key is 16B-granular within each 128B block (the rounds-3/4-verified
// conflict-free pattern: 128B rows, XOR bits 4-6 <- row bits 0-2).
__global__ void cvt_fp8(const float* __restrict__ in, unsigned char* __restrict__ out, int total16) {
  int idx = blockIdx.x * blockDim.x + threadIdx.x;
  int stride = gridDim.x * blockDim.x;
  for (; idx < total16; idx += stride) {
    unsigned row = (unsigned)idx >> 6;          // H_DIM/16 = 64 chunks per row
    unsigned k0 = ((unsigned)idx & 63u) << 4;
    const float4* p = (const float4*)(in + (size_t)row * H_DIM + k0);
    float4 f0 = p[0], f1 = p[1], f2 = p[2], f3 = p[3];
    unsigned long long u0 = (unsigned long long)pk4_fp8(f0.x, f0.y, f0.z, f0.w) |
                            ((unsigned long long)pk4_fp8(f1.x, f1.y, f1.z, f1.w) << 32);
    unsigned long long u1 = (unsigned long long)pk4_fp8(f2.x, f2.y, f2.z, f2.w) |
                            ((unsigned long long)pk4_fp8(f3.x, f3.y, f3.z, f3.w) << 32);
    unsigned key = (row & 7u) << 4;
    unsigned char* ob = out + (size_t)row * H_DIM;
    *(unsigned long long*)(ob + (k0 ^ key)) = u0;
    *(unsigned long long*)(ob + ((k0 ^ key) + 8u)) = u1;
  }
}

// 32B LDS fragment load as two ds_read_b128 (off is a literal -> imm-folded).
__device__ __forceinline__ i32x8 ld32(const char* lo, const char* hi, int off) {
  i32x4 a = *(const i32x4*)(lo + off);
  i32x4 b = *(const i32x4*)(hi + off);
  return __builtin_shufflevector(a, b, 0, 1, 2, 3, 4, 5, 6, 7);
}

// MX-scaled fp8 MFMA with unit scales (E8M0 127 = x1.0): numerically identical
// to plain e4m3 matmul but at the 4686 TF MX rate (2.2x the non-scaled rate).
__device__ __forceinline__ f32x16 mx_mfma(i32x8 a, i32x8 b, f32x16 c) {
  return __builtin_amdgcn_mfma_scale_f32_32x32x64_f8f6f4(
      a, b, c, 0 /*A=fp8*/, 0 /*B=fp8*/, 0, 0x7f7f7f7f, 0, 0x7f7f7f7f);
}

// Fused dual-GEMM (MX-fp8 32x32x64) + KL partial sums.
// grid = 512 (XCD-aware), 256 threads (4 waves, 2x2 of 64x64), BK=128.
// LDS: 4 tiles x [128 rows][128B] = 64KB, single-buffered, bulk-sync.
// Per row n: Zt = sum exp(t), U = sum exp(t)*(t-s), Zs = sum exp(s).
__global__ __launch_bounds__(256, 2) void fused_kl(
    const unsigned char* __restrict__ x8, const unsigned char* __restrict__ tx8,
    const unsigned char* __restrict__ ws8, const unsigned char* __restrict__ wt8,
    float* __restrict__ Zt, float* __restrict__ Uu, float* __restrict__ Zs) {
  __shared__ __align__(16) char smem[65536];  // x | tx | Ws | Wt (16KB each)

  const unsigned tid = threadIdx.x;
  const unsigned lane = tid & 63u;
  const unsigned w = tid >> 6;
  const unsigned wr = w >> 1, wc = w & 1;

  const unsigned b = blockIdx.x;
  const unsigned rb = (b & 7u) * 4u + ((b >> 3) & 3u);  // row-block 0..31
  const unsigned chunk = b >> 5;                        // vocab chunk 0..15
  const unsigned row0 = rb * 128u;
  const unsigned t_begin = chunk * 15u + (chunk < 10u ? chunk : 10u);
  const unsigned t_count = (chunk < 10u) ? 16u : 15u;

  // 32x32x64 fragment geometry: lane holds row rA = lane&31, K bytes
  // h*32 + ks*64 + [0..31] of the 128B row (h = lane>>5).
  const unsigned rA = lane & 31u;
  const unsigned h  = lane >> 5;
  const unsigned key = (rA & 7u) << 4;   // swizzle key (16B units, bits 4-6)

  // Loop-invariant ds_read pointers (single-buffered LDS -> same every k-step).
  // x tile at +0 (tx via offset:16384), Ws at +32768 (Wt via offset:16384).
  const char* pA[2][2][2];  // [mi][ks][q]
  const char* pB[2][2][2];  // [ni][ks][q]
#pragma unroll
  for (int mi = 0; mi < 2; ++mi)
#pragma unroll
    for (int ks = 0; ks < 2; ++ks)
#pragma unroll
      for (int q = 0; q < 2; ++q) {
        unsigned f = (((unsigned)ks << 6) | (h << 5) | ((unsigned)q << 4)) ^ key;
        pA[mi][ks][q] = smem + (wr * 64u + (unsigned)mi * 32u + rA) * 128u + f;
        pB[mi][ks][q] = smem + 32768u + (wc * 64u + (unsigned)mi * 32u + rA) * 128u + f;
      }

  // Staging: wave w stages its own 16KB tile; lane covers (row = i*8 + lane>>3,
  // 16B chunk lane&7); LDS dest linear (source layout is pre-swizzled).
  char* sdst = smem + w * 16384u + lane * 16u;
  const unsigned char* gsrc = (w == 0) ? x8 : (w == 1) ? tx8 : (w == 2) ? ws8 : wt8;
  const bool a_wave = (w < 2);
  const unsigned srow = lane >> 3;
  const unsigned sb = (lane & 7u) * 16u;

  float zt_m[2] = {0.f, 0.f}, uu_m[2] = {0.f, 0.f}, zs_m[2] = {0.f, 0.f};

  for (unsigned vt = 0; vt < t_count; ++vt) {
    const unsigned tile_row0 = a_wave ? row0 : (t_begin + vt) * 128u;
    const unsigned char* sv = gsrc + (size_t)(tile_row0 + srow) * H_DIM + sb;

    f32x16 acc_s[2][2], acc_t[2][2];
#pragma unroll
    for (int mi = 0; mi < 2; ++mi)
#pragma unroll
      for (int ni = 0; ni < 2; ++ni) {
        f32x16 z = {};
        acc_s[mi][ni] = z; acc_t[mi][ni] = z;
      }

    for (unsigned kt = 0; kt < 8; ++kt) {
      __syncthreads();  // previous step's ds_reads done before overwrite
      {
        const unsigned char* sk = sv + kt * 128u;
#pragma unroll
        for (unsigned i = 0; i < 16; ++i)
          __builtin_amdgcn_global_load_lds((gas_ptr)(sk + (size_t)i * (8u * H_DIM)),
                                           (las_ptr)(sdst + i * 1024u), 16, 0, 0);
      }
      __syncthreads();  // drains vmcnt(0) -> staging visible to all waves

#pragma unroll
      for (int ks = 0; ks < 2; ++ks) {
        // student GEMM (x tile, Ws tile)
        i32x8 a0 = ld32(pA[0][ks][0], pA[0][ks][1], 0);
        i32x8 a1 = ld32(pA[1][ks][0], pA[1][ks][1], 0);
        i32x8 bb = ld32(pB[0][ks][0], pB[0][ks][1], 0);
        acc_s[0][0] = mx_mfma(a0, bb, acc_s[0][0]);
        acc_s[1][0] = mx_mfma(a1, bb, acc_s[1][0]);
        bb = ld32(pB[1][ks][0], pB[1][ks][1], 0);
        acc_s[0][1] = mx_mfma(a0, bb, acc_s[0][1]);
        acc_s[1][1] = mx_mfma(a1, bb, acc_s[1][1]);
        // teacher GEMM (tx tile, Wt tile) via +16384 ds offset immediates
        a0 = ld32(pA[0][ks][0], pA[0][ks][1], 16384);
        a1 = ld32(pA[1][ks][0], pA[1][ks][1], 16384);
        bb = ld32(pB[0][ks][0], pB[0][ks][1], 16384);
        acc_t[0][0] = mx_mfma(a0, bb, acc_t[0][0]);
        acc_t[1][0] = mx_mfma(a1, bb, acc_t[1][0]);
        bb = ld32(pB[1][ks][0], pB[1][ks][1], 16384);
        acc_t[0][1] = mx_mfma(a0, bb, acc_t[0][1]);
        acc_t[1][1] = mx_mfma(a1, bb, acc_t[1][1]);
      }
    }

    // Epilogue: fold this 128-col logit tile into per-lane KL sums.
    // 32x32 C/D layout (m74/m101): col = lane&31, row = (reg&3)+8*(reg>>2)+4*h.
#pragma unroll
    for (int mi = 0; mi < 2; ++mi)
#pragma unroll
      for (int r = 0; r < 16; ++r) {
        float s0 = acc_s[mi][0][r], s1 = acc_s[mi][1][r];
        float t0 = acc_t[mi][0][r], t1 = acc_t[mi][1][r];
        float et0 = __expf(t0), et1 = __expf(t1);
        float ztl = et0 + et1;
        float uul = et0 * (t0 - s0) + et1 * (t1 - s1);
        float zsl = __expf(s0) + __expf(s1);
        ztl += __shfl_xor(ztl, 1); ztl += __shfl_xor(ztl, 2);
        ztl += __shfl_xor(ztl, 4); ztl += __shfl_xor(ztl, 8); ztl += __shfl_xor(ztl, 16);
        uul += __shfl_xor(uul, 1); uul += __shfl_xor(uul, 2);
        uul += __shfl_xor(uul, 4); uul += __shfl_xor(uul, 8); uul += __shfl_xor(uul, 16);
        zsl += __shfl_xor(zsl, 1); zsl += __shfl_xor(zsl, 2);
        zsl += __shfl_xor(zsl, 4); zsl += __shfl_xor(zsl, 8); zsl += __shfl_xor(zsl, 16);
        if ((int)(lane & 31u) == r) { zt_m[mi] += ztl; uu_m[mi] += uul; zs_m[mi] += zsl; }
      }
  }

  // Lanes with (lane&31) < 16 own one row per mi: row = (reg&3)+8*(reg>>2)+4*h.
  if ((lane & 31u) < 16u) {
    const unsigned reg = lane & 31u;
    const unsigned rrow = (reg & 3u) + 8u * (reg >> 2) + 4u * h;
#pragma unroll
    for (int mi = 0; mi < 2; ++mi) {
      unsigned n = row0 + wr * 64u + (unsigned)mi * 32u + rrow;
      atomicAdd(&Zt[n], zt_m[mi]);
      atomicAdd(&Uu[n], uu_m[mi]);
      atomicAdd(&Zs[n], zs_m[mi]);
    }
  }
}

// KL_n = U/Zt - log Zt + log Zs ; out = mean over N, float32.
__global__ void finalize_kl(const float* __restrict__ Zt, const float* __restrict__ Uu,
                            const float* __restrict__ Zs, float* __restrict__ out) {
  __shared__ float red[4];
  float s = 0.f;
  for (int r = threadIdx.x; r < N_ROWS; r += 256) {
    s += Uu[r] / Zt[r] - __logf(Zt[r]) + __logf(Zs[r]);
  }
  s += __shfl_xor(s, 1); s += __shfl_xor(s, 2); s += __shfl_xor(s, 4);
  s += __shfl_xor(s, 8); s += __shfl_xor(s, 16); s += __shfl_xor(s, 32);
  if ((threadIdx.x & 63) == 0) red[threadIdx.x >> 6] = s;
  __syncthreads();
  if (threadIdx.x == 0) {
    float tot = red[0] + red[1] + red[2] + red[3];
    out[0] = tot / (float)N_ROWS;
  }
}

extern "C" void kernel_launch(void* const* d_in, const int* in_sizes, int n_in,
                              void* d_out, int out_size, void* d_ws, size_t ws_size,
                              hipStream_t stream) {
  const float* x  = (const float*)d_in[0];
  const float* tx = (const float*)d_in[1];
  const float* Ws = (const float*)d_in[2];
  const float* Wt = (const float*)d_in[3];

  char* ws = (char*)d_ws;
  float* Zt = (float*)ws;
  float* Uu = Zt + N_ROWS;
  float* Zs = Uu + N_ROWS;
  unsigned char* x8  = (unsigned char*)(ws + 65536);
  unsigned char* tx8 = x8  + (size_t)N_ROWS * H_DIM;
  unsigned char* ws8 = tx8 + (size_t)N_ROWS * H_DIM;
  unsigned char* wt8 = ws8 + (size_t)V_SIZE * H_DIM;

  zero_f32<<<(3 * N_ROWS) / 256, 256, 0, stream>>>(Zt, 3 * N_ROWS);
  cvt_fp8<<<1024, 256, 0, stream>>>(x,  x8,  N_ROWS * (H_DIM / 16));
  cvt_fp8<<<1024, 256, 0, stream>>>(tx, tx8, N_ROWS * (H_DIM / 16));
  cvt_fp8<<<2048, 256, 0, stream>>>(Ws, ws8, V_SIZE * (H_DIM / 16));
  cvt_fp8<<<2048, 256, 0, stream>>>(Wt, wt8, V_SIZE * (H_DIM / 16));
  fused_kl<<<512, 256, 0, stream>>>(x8, tx8, ws8, wt8, Zt, Uu, Zs);
  finalize_kl<<<1, 256, 0, stream>>>(Zt, Uu, Zs, (float*)d_out);
}

// Round 7
// 478.856 us; speedup vs baseline: 5.3012x; 5.3012x over previous
//
#include <hip/hip_runtime.h>
#include <hip/hip_fp8.h>

#define N_ROWS 4096
#define H_DIM  1024
#define V_SIZE 32000

typedef int   i32x4 __attribute__((ext_vector_type(4)));
typedef float f32x4 __attribute__((ext_vector_type(4)));

typedef __attribute__((address_space(1))) void* gas_ptr;
typedef __attribute__((address_space(3))) void* las_ptr;

__global__ void zero_f32(float* __restrict__ p, int n) {
  int i = blockIdx.x * blockDim.x + threadIdx.x;
  if (i < n) p[i] = 0.0f;
}

__device__ __forceinline__ unsigned pk4_fp8(float a, float b, float c, float d) {
#if __has_builtin(__builtin_amdgcn_cvt_pk_fp8_f32)
  int v = __builtin_amdgcn_cvt_pk_fp8_f32(a, b, 0, false);
  v = __builtin_amdgcn_cvt_pk_fp8_f32(c, d, v, true);
  return (unsigned)v;
#else
  __hip_fp8_e4m3 qa(a), qb(b), qc(c), qd(d);
  return (unsigned)qa.__x | ((unsigned)qb.__x << 8) | ((unsigned)qc.__x << 16) |
         ((unsigned)qd.__x << 24);
#endif
}

// fp32 -> fp8 e4m3 with the LDS swizzle PRE-BAKED into the HBM layout:
// out[row*1024 + (k ^ ((row&7)<<4))] = fp8(in[row*1024 + k]).
// 16B-granular key within each 128B block (the r3/r4-verified conflict-free
// pattern: 128B rows, XOR byte-bits 4-6 <- row bits 0-2).
__global__ void cvt_fp8(const float* __restrict__ in, unsigned char* __restrict__ out, int total16) {
  int idx = blockIdx.x * blockDim.x + threadIdx.x;
  int stride = gridDim.x * blockDim.x;
  for (; idx < total16; idx += stride) {
    unsigned row = (unsigned)idx >> 6;          // H_DIM/16 = 64 chunks per row
    unsigned k0 = ((unsigned)idx & 63u) << 4;
    const float4* p = (const float4*)(in + (size_t)row * H_DIM + k0);
    float4 f0 = p[0], f1 = p[1], f2 = p[2], f3 = p[3];
    unsigned long long u0 = (unsigned long long)pk4_fp8(f0.x, f0.y, f0.z, f0.w) |
                            ((unsigned long long)pk4_fp8(f1.x, f1.y, f1.z, f1.w) << 32);
    unsigned long long u1 = (unsigned long long)pk4_fp8(f2.x, f2.y, f2.z, f2.w) |
                            ((unsigned long long)pk4_fp8(f3.x, f3.y, f3.z, f3.w) << 32);
    unsigned key = (row & 7u) << 4;
    unsigned char* ob = out + (size_t)row * H_DIM;
    *(unsigned long long*)(ob + (k0 ^ key)) = u0;
    *(unsigned long long*)(ob + ((k0 ^ key) + 8u)) = u1;
  }
}

__device__ __forceinline__ long long ll_lo(i32x4 v) {
  return (long long)(((unsigned long long)(unsigned)v[1] << 32) | (unsigned)v[0]);
}
__device__ __forceinline__ long long ll_hi(i32x4 v) {
  return (long long)(((unsigned long long)(unsigned)v[3] << 32) | (unsigned)v[2]);
}

// Fused dual-GEMM (fp8 e4m3 16x16x32 MFMA) + KL partial sums.
// grid = 512 (XCD-aware), 256 threads (4 waves, 2x2 of 64x64), BK=128.
// LDS: 4 tiles x [128 rows][128B] = 64KB, single-buffered, bulk-sync.
// Each lane's ds_read_b128 (16B) feeds 2 MFMAs (lo/hi 8B); the K-subset
// mapping is identical on A and B sides, so the contraction is exact.
// Per row n: Zt = sum exp(t), U = sum exp(t)*(t-s), Zs = sum exp(s).
__global__ __launch_bounds__(256, 2) void fused_kl(
    const unsigned char* __restrict__ x8, const unsigned char* __restrict__ tx8,
    const unsigned char* __restrict__ ws8, const unsigned char* __restrict__ wt8,
    float* __restrict__ Zt, float* __restrict__ Uu, float* __restrict__ Zs) {
  __shared__ __align__(16) char smem[65536];  // x | tx (+16KB) | Ws (+32KB) | Wt (+48KB)

  const unsigned tid = threadIdx.x;
  const unsigned lane = tid & 63u;
  const unsigned w = tid >> 6;
  const unsigned wr = w >> 1, wc = w & 1;

  const unsigned b = blockIdx.x;
  const unsigned rb = (b & 7u) * 4u + ((b >> 3) & 3u);  // row-block 0..31
  const unsigned chunk = b >> 5;                        // vocab chunk 0..15
  const unsigned row0 = rb * 128u;
  const unsigned t_begin = chunk * 15u + (chunk < 10u ? chunk : 10u);
  const unsigned t_count = (chunk < 10u) ? 16u : 15u;

  const unsigned c = lane & 15u;        // fragment row/col index
  const unsigned g = (lane >> 4) & 3u;  // K-group
  const unsigned key = (c & 7u) << 4;   // swizzle key (bits 4-6)

  // Loop-invariant base pointers (4 VGPRs); all other addressing via ds
  // offset immediates: + mi*2048 (16 rows x 128B), +16384 for teacher tile.
  // A byte addr: (wr*64 + mi*16 + c)*128 + ((kk2*64 + g*16) ^ key)
  const char* pA[2];
  const char* pB[2];
#pragma unroll
  for (int kk2 = 0; kk2 < 2; ++kk2) {
    unsigned f = (((unsigned)kk2 << 6) | (g << 4)) ^ key;
    pA[kk2] = smem + (wr * 64u + c) * 128u + f;
    pB[kk2] = smem + 32768u + (wc * 64u + c) * 128u + f;
  }

  // Staging: wave w stages its own 16KB tile (pre-swizzled source, linear LDS):
  // lane covers rows (lane>>3) + i*8, 16B chunk (lane&7)*16.
  char* sdst = smem + w * 16384u + lane * 16u;
  const unsigned char* gsrc = (w == 0) ? x8 : (w == 1) ? tx8 : (w == 2) ? ws8 : wt8;
  const bool a_wave = (w < 2);
  const unsigned srow = lane >> 3;
  const unsigned sb = (lane & 7u) * 16u;

  float zt1 = 0.f, uu1 = 0.f, zs1 = 0.f;
  const f32x4 fzero = {0.f, 0.f, 0.f, 0.f};

  for (unsigned vt = 0; vt < t_count; ++vt) {
    const unsigned tile_row0 = a_wave ? row0 : (t_begin + vt) * 128u;
    const unsigned char* sv = gsrc + (size_t)(tile_row0 + srow) * H_DIM + sb;

    f32x4 acc_s[4][4], acc_t[4][4];
#pragma unroll
    for (int mi = 0; mi < 4; ++mi)
#pragma unroll
      for (int ni = 0; ni < 4; ++ni) { acc_s[mi][ni] = fzero; acc_t[mi][ni] = fzero; }

    for (unsigned kt = 0; kt < 8; ++kt) {
      __syncthreads();  // previous step's ds_reads done before overwrite
      {
        const unsigned char* sk = sv + kt * 128u;
#pragma unroll
        for (unsigned i = 0; i < 16; ++i)
          __builtin_amdgcn_global_load_lds((gas_ptr)(sk + (size_t)i * (8u * H_DIM)),
                                           (las_ptr)(sdst + i * 1024u), 16, 0, 0);
      }
      __syncthreads();  // drains vmcnt(0) -> staging visible to all waves

#pragma unroll
      for (int kk2 = 0; kk2 < 2; ++kk2) {
        i32x4 axv[4], atv[4];
#pragma unroll
        for (int mi = 0; mi < 4; ++mi) {
          axv[mi] = *(const i32x4*)(pA[kk2] + mi * 2048);
          atv[mi] = *(const i32x4*)(pA[kk2] + mi * 2048 + 16384);
        }
#pragma unroll
        for (int ni = 0; ni < 4; ++ni) {
          i32x4 bsv = *(const i32x4*)(pB[kk2] + ni * 2048);
          i32x4 btv = *(const i32x4*)(pB[kk2] + ni * 2048 + 16384);
          long long bs0 = ll_lo(bsv), bs1 = ll_hi(bsv);
          long long bt0 = ll_lo(btv), bt1 = ll_hi(btv);
#pragma unroll
          for (int mi = 0; mi < 4; ++mi) {
            acc_s[mi][ni] = __builtin_amdgcn_mfma_f32_16x16x32_fp8_fp8(ll_lo(axv[mi]), bs0, acc_s[mi][ni], 0, 0, 0);
            acc_s[mi][ni] = __builtin_amdgcn_mfma_f32_16x16x32_fp8_fp8(ll_hi(axv[mi]), bs1, acc_s[mi][ni], 0, 0, 0);
            acc_t[mi][ni] = __builtin_amdgcn_mfma_f32_16x16x32_fp8_fp8(ll_lo(atv[mi]), bt0, acc_t[mi][ni], 0, 0, 0);
            acc_t[mi][ni] = __builtin_amdgcn_mfma_f32_16x16x32_fp8_fp8(ll_hi(atv[mi]), bt1, acc_t[mi][ni], 0, 0, 0);
          }
        }
      }
    }

    // Epilogue: fold this 128-col logit tile into per-lane KL sums.
    // C/D layout: col = lane&15, row = (lane>>4)*4 + j (m89-verified)
#pragma unroll
    for (int mi = 0; mi < 4; ++mi)
#pragma unroll
      for (int j = 0; j < 4; ++j) {
        float ztl = 0.f, uul = 0.f, zsl = 0.f;
#pragma unroll
        for (int ni = 0; ni < 4; ++ni) {
          float s = acc_s[mi][ni][j];
          float tt = acc_t[mi][ni][j];
          float et = __expf(tt);
          ztl += et;
          uul += et * (tt - s);
          zsl += __expf(s);
        }
        ztl += __shfl_xor(ztl, 1); ztl += __shfl_xor(ztl, 2);
        ztl += __shfl_xor(ztl, 4); ztl += __shfl_xor(ztl, 8);
        uul += __shfl_xor(uul, 1); uul += __shfl_xor(uul, 2);
        uul += __shfl_xor(uul, 4); uul += __shfl_xor(uul, 8);
        zsl += __shfl_xor(zsl, 1); zsl += __shfl_xor(zsl, 2);
        zsl += __shfl_xor(zsl, 4); zsl += __shfl_xor(zsl, 8);
        if (c == (unsigned)(mi * 4 + j)) { zt1 += ztl; uu1 += uul; zs1 += zsl; }
      }
  }

  // Lane (g,c) owns row: wr*64 + (c>>2)*16 + g*4 + (c&3)  (bijective over 64 rows)
  {
    unsigned n = row0 + wr * 64u + (c >> 2) * 16u + g * 4u + (c & 3u);
    atomicAdd(&Zt[n], zt1);
    atomicAdd(&Uu[n], uu1);
    atomicAdd(&Zs[n], zs1);
  }
}

// KL_n = U/Zt - log Zt + log Zs ; out = mean over N, float32.
__global__ void finalize_kl(const float* __restrict__ Zt, const float* __restrict__ Uu,
                            const float* __restrict__ Zs, float* __restrict__ out) {
  __shared__ float red[4];
  float s = 0.f;
  for (int r = threadIdx.x; r < N_ROWS; r += 256) {
    s += Uu[r] / Zt[r] - __logf(Zt[r]) + __logf(Zs[r]);
  }
  s += __shfl_xor(s, 1); s += __shfl_xor(s, 2); s += __shfl_xor(s, 4);
  s += __shfl_xor(s, 8); s += __shfl_xor(s, 16); s += __shfl_xor(s, 32);
  if ((threadIdx.x & 63) == 0) red[threadIdx.x >> 6] = s;
  __syncthreads();
  if (threadIdx.x == 0) {
    float tot = red[0] + red[1] + red[2] + red[3];
    out[0] = tot / (float)N_ROWS;
  }
}

extern "C" void kernel_launch(void* const* d_in, const int* in_sizes, int n_in,
                              void* d_out, int out_size, void* d_ws, size_t ws_size,
                              hipStream_t stream) {
  const float* x  = (const float*)d_in[0];
  const float* tx = (const float*)d_in[1];
  const float* Ws = (const float*)d_in[2];
  const float* Wt = (const float*)d_in[3];

  char* ws = (char*)d_ws;
  float* Zt = (float*)ws;
  float* Uu = Zt + N_ROWS;
  float* Zs = Uu + N_ROWS;
  unsigned char* x8  = (unsigned char*)(ws + 65536);
  unsigned char* tx8 = x8  + (size_t)N_ROWS * H_DIM;
  unsigned char* ws8 = tx8 + (size_t)N_ROWS * H_DIM;
  unsigned char* wt8 = ws8 + (size_t)V_SIZE * H_DIM;

  zero_f32<<<(3 * N_ROWS) / 256, 256, 0, stream>>>(Zt, 3 * N_ROWS);
  cvt_fp8<<<1024, 256, 0, stream>>>(x,  x8,  N_ROWS * (H_DIM / 16));
  cvt_fp8<<<1024, 256, 0, stream>>>(tx, tx8, N_ROWS * (H_DIM / 16));
  cvt_fp8<<<2048, 256, 0, stream>>>(Ws, ws8, V_SIZE * (H_DIM / 16));
  cvt_fp8<<<2048, 256, 0, stream>>>(Wt, wt8, V_SIZE * (H_DIM / 16));
  fused_kl<<<512, 256, 0, stream>>>(x8, tx8, ws8, wt8, Zt, Uu, Zs);
  finalize_kl<<<1, 256, 0, stream>>>(Zt, Uu, Zs, (float*)d_out);
}

// Round 8
// 430.710 us; speedup vs baseline: 5.8938x; 1.1118x over previous
//
#include <hip/hip_runtime.h>
#include <hip/hip_fp8.h>

#define N_ROWS 4096
#define H_DIM  1024
#define V_SIZE 32000

typedef int   i32x4 __attribute__((ext_vector_type(4)));
typedef int   i32x8 __attribute__((ext_vector_type(8)));
typedef float f32x4 __attribute__((ext_vector_type(4)));

typedef __attribute__((address_space(1))) void* gas_ptr;
typedef __attribute__((address_space(3))) void* las_ptr;

__global__ void zero_f32(float* __restrict__ p, int n) {
  int i = blockIdx.x * blockDim.x + threadIdx.x;
  if (i < n) p[i] = 0.0f;
}

__device__ __forceinline__ unsigned pk4_fp8(float a, float b, float c, float d) {
#if __has_builtin(__builtin_amdgcn_cvt_pk_fp8_f32)
  int v = __builtin_amdgcn_cvt_pk_fp8_f32(a, b, 0, false);
  v = __builtin_amdgcn_cvt_pk_fp8_f32(c, d, v, true);
  return (unsigned)v;
#else
  __hip_fp8_e4m3 qa(a), qb(b), qc(c), qd(d);
  return (unsigned)qa.__x | ((unsigned)qb.__x << 8) | ((unsigned)qc.__x << 16) |
         ((unsigned)qd.__x << 24);
#endif
}

// fp32 -> fp8 e4m3 with the LDS swizzle PRE-BAKED into the HBM layout:
// out[row*1024 + (k ^ ((row&7)<<4))] = fp8(in[row*1024 + k]).
// 16B-granular key within each 128B block (the r3/r7-verified conflict-free
// pattern: 128B rows, XOR byte-bits 4-6 <- row bits 0-2).
__global__ void cvt_fp8(const float* __restrict__ in, unsigned char* __restrict__ out, int total16) {
  int idx = blockIdx.x * blockDim.x + threadIdx.x;
  int stride = gridDim.x * blockDim.x;
  for (; idx < total16; idx += stride) {
    unsigned row = (unsigned)idx >> 6;          // H_DIM/16 = 64 chunks per row
    unsigned k0 = ((unsigned)idx & 63u) << 4;
    const float4* p = (const float4*)(in + (size_t)row * H_DIM + k0);
    float4 f0 = p[0], f1 = p[1], f2 = p[2], f3 = p[3];
    unsigned long long u0 = (unsigned long long)pk4_fp8(f0.x, f0.y, f0.z, f0.w) |
                            ((unsigned long long)pk4_fp8(f1.x, f1.y, f1.z, f1.w) << 32);
    unsigned long long u1 = (unsigned long long)pk4_fp8(f2.x, f2.y, f2.z, f2.w) |
                            ((unsigned long long)pk4_fp8(f3.x, f3.y, f3.z, f3.w) << 32);
    unsigned key = (row & 7u) << 4;
    unsigned char* ob = out + (size_t)row * H_DIM;
    *(unsigned long long*)(ob + (k0 ^ key)) = u0;
    *(unsigned long long*)(ob + ((k0 ^ key) + 8u)) = u1;
  }
}

__device__ __forceinline__ i32x8 cat8(i32x4 a, i32x4 b) {
  return __builtin_shufflevector(a, b, 0, 1, 2, 3, 4, 5, 6, 7);
}

// MX-scaled fp8 MFMA, unit scales (E8M0 127 = x1.0): numerically identical to
// plain e4m3 matmul but at the 4661 TF MX rate (2.25x non-scaled). The 16x16
// shape keeps C/D at 4 f32/lane (r7's proven no-spill acc footprint); arg
// pattern validated by round 6 (correct results with 32x32x64).
__device__ __forceinline__ f32x4 mx_mfma(i32x8 a, i32x8 b, f32x4 c) {
  return __builtin_amdgcn_mfma_scale_f32_16x16x128_f8f6f4(
      a, b, c, 0 /*A=fp8*/, 0 /*B=fp8*/, 0, 0x7f7f7f7f, 0, 0x7f7f7f7f);
}

// Fused dual-GEMM (MX-fp8 16x16x128) + KL partial sums.
// grid = 512 (XCD-aware), 256 threads (4 waves, 2x2 of 64x64), BK=128.
// LDS: 4 tiles x [128 rows][128B] = 64KB, single-buffered, bulk-sync.
// Fragment: lane holds row (lane&15), K bytes (lane>>4)*32..+31 = the two 16B
// swizzle units it reads (same mapping on A and B sides -> exact contraction).
// Per row n: Zt = sum exp(t), U = sum exp(t)*(t-s), Zs = sum exp(s).
__global__ __launch_bounds__(256, 2) void fused_kl(
    const unsigned char* __restrict__ x8, const unsigned char* __restrict__ tx8,
    const unsigned char* __restrict__ ws8, const unsigned char* __restrict__ wt8,
    float* __restrict__ Zt, float* __restrict__ Uu, float* __restrict__ Zs) {
  __shared__ __align__(16) char smem[65536];  // x | tx (+16KB) | Ws (+32KB) | Wt (+48KB)

  const unsigned tid = threadIdx.x;
  const unsigned lane = tid & 63u;
  const unsigned w = tid >> 6;
  const unsigned wr = w >> 1, wc = w & 1;

  const unsigned b = blockIdx.x;
  const unsigned rb = (b & 7u) * 4u + ((b >> 3) & 3u);  // row-block 0..31
  const unsigned chunk = b >> 5;                        // vocab chunk 0..15
  const unsigned row0 = rb * 128u;
  const unsigned t_begin = chunk * 15u + (chunk < 10u ? chunk : 10u);
  const unsigned t_count = (chunk < 10u) ? 16u : 15u;

  const unsigned c = lane & 15u;        // fragment row/col index
  const unsigned g = (lane >> 4) & 3u;  // K-group (32B each)
  const unsigned key = (c & 7u) << 4;   // swizzle key (bits 4-6)

  // Loop-invariant base pointers (4 VGPRs); other addressing via ds offset
  // immediates: + mi*2048 (16 rows x 128B), +16384 for the teacher tile.
  // Unit q of lane's 32B: byte ((g<<5)|(q<<4)) ^ key = f0 ^ (q*16).
  const unsigned f0 = (g << 5) ^ key;
  const char* pA0 = smem + (wr * 64u + c) * 128u + f0;
  const char* pA1 = smem + (wr * 64u + c) * 128u + (f0 ^ 16u);
  const char* pB0 = smem + 32768u + (wc * 64u + c) * 128u + f0;
  const char* pB1 = smem + 32768u + (wc * 64u + c) * 128u + (f0 ^ 16u);

  // Staging: wave w stages its own 16KB tile (pre-swizzled source, linear LDS):
  // lane covers rows (lane>>3) + i*8, 16B chunk (lane&7)*16.
  char* sdst = smem + w * 16384u + lane * 16u;
  const unsigned char* gsrc = (w == 0) ? x8 : (w == 1) ? tx8 : (w == 2) ? ws8 : wt8;
  const bool a_wave = (w < 2);
  const unsigned srow = lane >> 3;
  const unsigned sb = (lane & 7u) * 16u;

  float zt1 = 0.f, uu1 = 0.f, zs1 = 0.f;
  const f32x4 fzero = {0.f, 0.f, 0.f, 0.f};

  for (unsigned vt = 0; vt < t_count; ++vt) {
    const unsigned tile_row0 = a_wave ? row0 : (t_begin + vt) * 128u;
    const unsigned char* sv = gsrc + (size_t)(tile_row0 + srow) * H_DIM + sb;

    f32x4 acc_s[4][4], acc_t[4][4];
#pragma unroll
    for (int mi = 0; mi < 4; ++mi)
#pragma unroll
      for (int ni = 0; ni < 4; ++ni) { acc_s[mi][ni] = fzero; acc_t[mi][ni] = fzero; }

    for (unsigned kt = 0; kt < 8; ++kt) {
      __syncthreads();  // previous step's ds_reads done before overwrite
      {
        const unsigned char* sk = sv + kt * 128u;
#pragma unroll
        for (unsigned i = 0; i < 16; ++i)
          __builtin_amdgcn_global_load_lds((gas_ptr)(sk + (size_t)i * (8u * H_DIM)),
                                           (las_ptr)(sdst + i * 1024u), 16, 0, 0);
      }
      __syncthreads();  // drains vmcnt(0) -> staging visible to all waves

      // ---- student pass (x, Ws) ----
      {
        i32x8 ax[4];
#pragma unroll
        for (int mi = 0; mi < 4; ++mi)
          ax[mi] = cat8(*(const i32x4*)(pA0 + mi * 2048),
                        *(const i32x4*)(pA1 + mi * 2048));
#pragma unroll
        for (int ni = 0; ni < 4; ++ni) {
          i32x8 bs = cat8(*(const i32x4*)(pB0 + ni * 2048),
                          *(const i32x4*)(pB1 + ni * 2048));
#pragma unroll
          for (int mi = 0; mi < 4; ++mi)
            acc_s[mi][ni] = mx_mfma(ax[mi], bs, acc_s[mi][ni]);
        }
      }
      // ---- teacher pass (tx, Wt) via +16384 ds offset immediates ----
      {
        i32x8 at[4];
#pragma unroll
        for (int mi = 0; mi < 4; ++mi)
          at[mi] = cat8(*(const i32x4*)(pA0 + mi * 2048 + 16384),
                        *(const i32x4*)(pA1 + mi * 2048 + 16384));
#pragma unroll
        for (int ni = 0; ni < 4; ++ni) {
          i32x8 bt = cat8(*(const i32x4*)(pB0 + ni * 2048 + 16384),
                          *(const i32x4*)(pB1 + ni * 2048 + 16384));
#pragma unroll
          for (int mi = 0; mi < 4; ++mi)
            acc_t[mi][ni] = mx_mfma(at[mi], bt, acc_t[mi][ni]);
        }
      }
    }

    // Epilogue: fold this 128-col logit tile into per-lane KL sums.
    // C/D layout: col = lane&15, row = (lane>>4)*4 + j (m89-verified,
    // shape-determined, dtype/scale-independent).
#pragma unroll
    for (int mi = 0; mi < 4; ++mi)
#pragma unroll
      for (int j = 0; j < 4; ++j) {
        float ztl = 0.f, uul = 0.f, zsl = 0.f;
#pragma unroll
        for (int ni = 0; ni < 4; ++ni) {
          float s = acc_s[mi][ni][j];
          float tt = acc_t[mi][ni][j];
          float et = __expf(tt);
          ztl += et;
          uul += et * (tt - s);
          zsl += __expf(s);
        }
        ztl += __shfl_xor(ztl, 1); ztl += __shfl_xor(ztl, 2);
        ztl += __shfl_xor(ztl, 4); ztl += __shfl_xor(ztl, 8);
        uul += __shfl_xor(uul, 1); uul += __shfl_xor(uul, 2);
        uul += __shfl_xor(uul, 4); uul += __shfl_xor(uul, 8);
        zsl += __shfl_xor(zsl, 1); zsl += __shfl_xor(zsl, 2);
        zsl += __shfl_xor(zsl, 4); zsl += __shfl_xor(zsl, 8);
        if (c == (unsigned)(mi * 4 + j)) { zt1 += ztl; uu1 += uul; zs1 += zsl; }
      }
  }

  // Lane (g,c) owns row: wr*64 + (c>>2)*16 + g*4 + (c&3)  (bijective over 64 rows)
  {
    unsigned n = row0 + wr * 64u + (c >> 2) * 16u + g * 4u + (c & 3u);
    atomicAdd(&Zt[n], zt1);
    atomicAdd(&Uu[n], uu1);
    atomicAdd(&Zs[n], zs1);
  }
}

// KL_n = U/Zt - log Zt + log Zs ; out = mean over N, float32.
__global__ void finalize_kl(const float* __restrict__ Zt, const float* __restrict__ Uu,
                            const float* __restrict__ Zs, float* __restrict__ out) {
  __shared__ float red[4];
  float s = 0.f;
  for (int r = threadIdx.x; r < N_ROWS; r += 256) {
    s += Uu[r] / Zt[r] - __logf(Zt[r]) + __logf(Zs[r]);
  }
  s += __shfl_xor(s, 1); s += __shfl_xor(s, 2); s += __shfl_xor(s, 4);
  s += __shfl_xor(s, 8); s += __shfl_xor(s, 16); s += __shfl_xor(s, 32);
  if ((threadIdx.x & 63) == 0) red[threadIdx.x >> 6] = s;
  __syncthreads();
  if (threadIdx.x == 0) {
    float tot = red[0] + red[1] + red[2] + red[3];
    out[0] = tot / (float)N_ROWS;
  }
}

extern "C" void kernel_launch(void* const* d_in, const int* in_sizes, int n_in,
                              void* d_out, int out_size, void* d_ws, size_t ws_size,
                              hipStream_t stream) {
  const float* x  = (const float*)d_in[0];
  const float* tx = (const float*)d_in[1];
  const float* Ws = (const float*)d_in[2];
  const float* Wt = (const float*)d_in[3];

  char* ws = (char*)d_ws;
  float* Zt = (float*)ws;
  float* Uu = Zt + N_ROWS;
  float* Zs = Uu + N_ROWS;
  unsigned char* x8  = (unsigned char*)(ws + 65536);
  unsigned char* tx8 = x8  + (size_t)N_ROWS * H_DIM;
  unsigned char* ws8 = tx8 + (size_t)N_ROWS * H_DIM;
  unsigned char* wt8 = ws8 + (size_t)V_SIZE * H_DIM;

  zero_f32<<<(3 * N_ROWS) / 256, 256, 0, stream>>>(Zt, 3 * N_ROWS);
  cvt_fp8<<<1024, 256, 0, stream>>>(x,  x8,  N_ROWS * (H_DIM / 16));
  cvt_fp8<<<1024, 256, 0, stream>>>(tx, tx8, N_ROWS * (H_DIM / 16));
  cvt_fp8<<<2048, 256, 0, stream>>>(Ws, ws8, V_SIZE * (H_DIM / 16));
  cvt_fp8<<<2048, 256, 0, stream>>>(Wt, wt8, V_SIZE * (H_DIM / 16));
  fused_kl<<<512, 256, 0, stream>>>(x8, tx8, ws8, wt8, Zt, Uu, Zs);
  finalize_kl<<<1, 256, 0, stream>>>(Zt, Uu, Zs, (float*)d_out);
}

// Round 9
// 409.189 us; speedup vs baseline: 6.2038x; 1.0526x over previous
//
#include <hip/hip_runtime.h>
#include <hip/hip_fp8.h>

#define N_ROWS 4096
#define H_DIM  1024
#define V_SIZE 32000

typedef int   i32x4 __attribute__((ext_vector_type(4)));
typedef int   i32x8 __attribute__((ext_vector_type(8)));
typedef float f32x4 __attribute__((ext_vector_type(4)));

typedef __attribute__((address_space(1))) void* gas_ptr;
typedef __attribute__((address_space(3))) void* las_ptr;

__global__ void zero_f32(float* __restrict__ p, int n) {
  int i = blockIdx.x * blockDim.x + threadIdx.x;
  if (i < n) p[i] = 0.0f;
}

__device__ __forceinline__ unsigned pk4_fp8(float a, float b, float c, float d) {
#if __has_builtin(__builtin_amdgcn_cvt_pk_fp8_f32)
  int v = __builtin_amdgcn_cvt_pk_fp8_f32(a, b, 0, false);
  v = __builtin_amdgcn_cvt_pk_fp8_f32(c, d, v, true);
  return (unsigned)v;
#else
  __hip_fp8_e4m3 qa(a), qb(b), qc(c), qd(d);
  return (unsigned)qa.__x | ((unsigned)qb.__x << 8) | ((unsigned)qc.__x << 16) |
         ((unsigned)qd.__x << 24);
#endif
}

// fp32 -> fp8 e4m3 with the LDS swizzle PRE-BAKED into the HBM layout:
// out[row*1024 + (k ^ ((row&7)<<4))] = fp8(in[row*1024 + k]).
// 16B-granular key within each 128B block (the r3/r7-verified conflict-free
// pattern: 128B rows, XOR byte-bits 4-6 <- row bits 0-2).
__global__ void cvt_fp8(const float* __restrict__ in, unsigned char* __restrict__ out, int total16) {
  int idx = blockIdx.x * blockDim.x + threadIdx.x;
  int stride = gridDim.x * blockDim.x;
  for (; idx < total16; idx += stride) {
    unsigned row = (unsigned)idx >> 6;          // H_DIM/16 = 64 chunks per row
    unsigned k0 = ((unsigned)idx & 63u) << 4;
    const float4* p = (const float4*)(in + (size_t)row * H_DIM + k0);
    float4 f0 = p[0], f1 = p[1], f2 = p[2], f3 = p[3];
    unsigned long long u0 = (unsigned long long)pk4_fp8(f0.x, f0.y, f0.z, f0.w) |
                            ((unsigned long long)pk4_fp8(f1.x, f1.y, f1.z, f1.w) << 32);
    unsigned long long u1 = (unsigned long long)pk4_fp8(f2.x, f2.y, f2.z, f2.w) |
                            ((unsigned long long)pk4_fp8(f3.x, f3.y, f3.z, f3.w) << 32);
    unsigned key = (row & 7u) << 4;
    unsigned char* ob = out + (size_t)row * H_DIM;
    *(unsigned long long*)(ob + (k0 ^ key)) = u0;
    *(unsigned long long*)(ob + ((k0 ^ key) + 8u)) = u1;
  }
}

__device__ __forceinline__ i32x8 cat8(i32x4 a, i32x4 b) {
  return __builtin_shufflevector(a, b, 0, 1, 2, 3, 4, 5, 6, 7);
}

// MX-scaled fp8 MFMA, unit scales (E8M0 127 = x1.0): numerically identical to
// plain e4m3 matmul at the 4661 TF MX rate (2.25x non-scaled). Validated r8.
__device__ __forceinline__ f32x4 mx_mfma(i32x8 a, i32x8 b, f32x4 c) {
  return __builtin_amdgcn_mfma_scale_f32_16x16x128_f8f6f4(
      a, b, c, 0 /*A=fp8*/, 0 /*B=fp8*/, 0, 0x7f7f7f7f, 0, 0x7f7f7f7f);
}

// Fused dual-GEMM (MX-fp8 16x16x128) + KL partial sums.
// grid = 512 (XCD-aware), 256 threads (4 waves, 2x2 of 64x64), BK=128.
// LDS: 4 tiles x [128 rows][128B] = 64KB, single-buffered, bulk-sync.
// ds_read addressing is r7's EXACT (HW-verified 0-conflict) stream:
// lane (c,g) reads physical unit (4*kk2+g)^(c&7) of its row for kk2=0,1.
// With the pre-swizzled HBM layout, that is logical K-unit {g, g+4} -- the
// SAME fixed K-permutation on A and B sides, so the K=128 contraction is
// exact (r8 validated this permutation-invariance with a different mapping).
// Per row n: Zt = sum exp(t), U = sum exp(t)*(t-s), Zs = sum exp(s).
__global__ __launch_bounds__(256, 2) void fused_kl(
    const unsigned char* __restrict__ x8, const unsigned char* __restrict__ tx8,
    const unsigned char* __restrict__ ws8, const unsigned char* __restrict__ wt8,
    float* __restrict__ Zt, float* __restrict__ Uu, float* __restrict__ Zs) {
  __shared__ __align__(16) char smem[65536];  // x | tx (+16KB) | Ws (+32KB) | Wt (+48KB)

  const unsigned tid = threadIdx.x;
  const unsigned lane = tid & 63u;
  const unsigned w = tid >> 6;
  const unsigned wr = w >> 1, wc = w & 1;

  const unsigned b = blockIdx.x;
  const unsigned rb = (b & 7u) * 4u + ((b >> 3) & 3u);  // row-block 0..31
  const unsigned chunk = b >> 5;                        // vocab chunk 0..15
  const unsigned row0 = rb * 128u;
  const unsigned t_begin = chunk * 15u + (chunk < 10u ? chunk : 10u);
  const unsigned t_count = (chunk < 10u) ? 16u : 15u;

  const unsigned c = lane & 15u;        // fragment row/col index
  const unsigned g = (lane >> 4) & 3u;  // K-group
  const unsigned key = (c & 7u) << 4;   // swizzle key (bits 4-6)

  // r7's loop-invariant base pointers (4 VGPRs); other addressing via ds
  // offset immediates: + mi*2048 (16 rows x 128B), +16384 for teacher tile.
  const char* pA[2];
  const char* pB[2];
#pragma unroll
  for (int kk2 = 0; kk2 < 2; ++kk2) {
    unsigned f = (((unsigned)kk2 << 6) | (g << 4)) ^ key;
    pA[kk2] = smem + (wr * 64u + c) * 128u + f;
    pB[kk2] = smem + 32768u + (wc * 64u + c) * 128u + f;
  }

  // Staging: wave w stages its own 16KB tile (pre-swizzled source, linear LDS):
  // lane covers rows (lane>>3) + i*8, 16B chunk (lane&7)*16.
  char* sdst = smem + w * 16384u + lane * 16u;
  const unsigned char* gsrc = (w == 0) ? x8 : (w == 1) ? tx8 : (w == 2) ? ws8 : wt8;
  const bool a_wave = (w < 2);
  const unsigned srow = lane >> 3;
  const unsigned sb = (lane & 7u) * 16u;

  float zt1 = 0.f, uu1 = 0.f, zs1 = 0.f;
  const f32x4 fzero = {0.f, 0.f, 0.f, 0.f};

  for (unsigned vt = 0; vt < t_count; ++vt) {
    const unsigned tile_row0 = a_wave ? row0 : (t_begin + vt) * 128u;
    const unsigned char* sv = gsrc + (size_t)(tile_row0 + srow) * H_DIM + sb;

    f32x4 acc_s[4][4], acc_t[4][4];
#pragma unroll
    for (int mi = 0; mi < 4; ++mi)
#pragma unroll
      for (int ni = 0; ni < 4; ++ni) { acc_s[mi][ni] = fzero; acc_t[mi][ni] = fzero; }

    for (unsigned kt = 0; kt < 8; ++kt) {
      __syncthreads();  // previous step's ds_reads done before overwrite
      {
        const unsigned char* sk = sv + kt * 128u;
#pragma unroll
        for (unsigned i = 0; i < 16; ++i)
          __builtin_amdgcn_global_load_lds((gas_ptr)(sk + (size_t)i * (8u * H_DIM)),
                                           (las_ptr)(sdst + i * 1024u), 16, 0, 0);
      }
      __syncthreads();  // drains vmcnt(0) -> staging visible to all waves

      // ---- student pass (x, Ws) ----
      {
        i32x8 ax[4];
#pragma unroll
        for (int mi = 0; mi < 4; ++mi)
          ax[mi] = cat8(*(const i32x4*)(pA[0] + mi * 2048),
                        *(const i32x4*)(pA[1] + mi * 2048));
#pragma unroll
        for (int ni = 0; ni < 4; ++ni) {
          i32x8 bs = cat8(*(const i32x4*)(pB[0] + ni * 2048),
                          *(const i32x4*)(pB[1] + ni * 2048));
#pragma unroll
          for (int mi = 0; mi < 4; ++mi)
            acc_s[mi][ni] = mx_mfma(ax[mi], bs, acc_s[mi][ni]);
        }
      }
      // ---- teacher pass (tx, Wt) via +16384 ds offset immediates ----
      {
        i32x8 at[4];
#pragma unroll
        for (int mi = 0; mi < 4; ++mi)
          at[mi] = cat8(*(const i32x4*)(pA[0] + mi * 2048 + 16384),
                        *(const i32x4*)(pA[1] + mi * 2048 + 16384));
#pragma unroll
        for (int ni = 0; ni < 4; ++ni) {
          i32x8 bt = cat8(*(const i32x4*)(pB[0] + ni * 2048 + 16384),
                          *(const i32x4*)(pB[1] + ni * 2048 + 16384));
#pragma unroll
          for (int mi = 0; mi < 4; ++mi)
            acc_t[mi][ni] = mx_mfma(at[mi], bt, acc_t[mi][ni]);
        }
      }
    }

    // Epilogue: fold this 128-col logit tile into per-lane KL sums.
    // C/D layout: col = lane&15, row = (lane>>4)*4 + j (m89-verified,
    // shape-determined, dtype/scale-independent).
#pragma unroll
    for (int mi = 0; mi < 4; ++mi)
#pragma unroll
      for (int j = 0; j < 4; ++j) {
        float ztl = 0.f, uul = 0.f, zsl = 0.f;
#pragma unroll
        for (int ni = 0; ni < 4; ++ni) {
          float s = acc_s[mi][ni][j];
          float tt = acc_t[mi][ni][j];
          float et = __expf(tt);
          ztl += et;
          uul += et * (tt - s);
          zsl += __expf(s);
        }
        ztl += __shfl_xor(ztl, 1); ztl += __shfl_xor(ztl, 2);
        ztl += __shfl_xor(ztl, 4); ztl += __shfl_xor(ztl, 8);
        uul += __shfl_xor(uul, 1); uul += __shfl_xor(uul, 2);
        uul += __shfl_xor(uul, 4); uul += __shfl_xor(uul, 8);
        zsl += __shfl_xor(zsl, 1); zsl += __shfl_xor(zsl, 2);
        zsl += __shfl_xor(zsl, 4); zsl += __shfl_xor(zsl, 8);
        if (c == (unsigned)(mi * 4 + j)) { zt1 += ztl; uu1 += uul; zs1 += zsl; }
      }
  }

  // Lane (g,c) owns row: wr*64 + (c>>2)*16 + g*4 + (c&3)  (bijective over 64 rows)
  {
    unsigned n = row0 + wr * 64u + (c >> 2) * 16u + g * 4u + (c & 3u);
    atomicAdd(&Zt[n], zt1);
    atomicAdd(&Uu[n], uu1);
    atomicAdd(&Zs[n], zs1);
  }
}

// KL_n = U/Zt - log Zt + log Zs ; out = mean over N, float32.
__global__ void finalize_kl(const float* __restrict__ Zt, const float* __restrict__ Uu,
                            const float* __restrict__ Zs, float* __restrict__ out) {
  __shared__ float red[4];
  float s = 0.f;
  for (int r = threadIdx.x; r < N_ROWS; r += 256) {
    s += Uu[r] / Zt[r] - __logf(Zt[r]) + __logf(Zs[r]);
  }
  s += __shfl_xor(s, 1); s += __shfl_xor(s, 2); s += __shfl_xor(s, 4);
  s += __shfl_xor(s, 8); s += __shfl_xor(s, 16); s += __shfl_xor(s, 32);
  if ((threadIdx.x & 63) == 0) red[threadIdx.x >> 6] = s;
  __syncthreads();
  if (threadIdx.x == 0) {
    float tot = red[0] + red[1] + red[2] + red[3];
    out[0] = tot / (float)N_ROWS;
  }
}

extern "C" void kernel_launch(void* const* d_in, const int* in_sizes, int n_in,
                              void* d_out, int out_size, void* d_ws, size_t ws_size,
                              hipStream_t stream) {
  const float* x  = (const float*)d_in[0];
  const float* tx = (const float*)d_in[1];
  const float* Ws = (const float*)d_in[2];
  const float* Wt = (const float*)d_in[3];

  char* ws = (char*)d_ws;
  float* Zt = (float*)ws;
  float* Uu = Zt + N_ROWS;
  float* Zs = Uu + N_ROWS;
  unsigned char* x8  = (unsigned char*)(ws + 65536);
  unsigned char* tx8 = x8  + (size_t)N_ROWS * H_DIM;
  unsigned char* ws8 = tx8 + (size_t)N_ROWS * H_DIM;
  unsigned char* wt8 = ws8 + (size_t)V_SIZE * H_DIM;

  zero_f32<<<(3 * N_ROWS) / 256, 256, 0, stream>>>(Zt, 3 * N_ROWS);
  cvt_fp8<<<1024, 256, 0, stream>>>(x,  x8,  N_ROWS * (H_DIM / 16));
  cvt_fp8<<<1024, 256, 0, stream>>>(tx, tx8, N_ROWS * (H_DIM / 16));
  cvt_fp8<<<2048, 256, 0, stream>>>(Ws, ws8, V_SIZE * (H_DIM / 16));
  cvt_fp8<<<2048, 256, 0, stream>>>(Wt, wt8, V_SIZE * (H_DIM / 16));
  fused_kl<<<512, 256, 0, stream>>>(x8, tx8, ws8, wt8, Zt, Uu, Zs);
  finalize_kl<<<1, 256, 0, stream>>>(Zt, Uu, Zs, (float*)d_out);
}